// Round 7
// baseline (1217.748 us; speedup 1.0000x reference)
//
#include <hip/hip_runtime.h>
#include <hip/hip_cooperative_groups.h>

namespace cg = cooperative_groups;

// Problem constants (match reference)
#define NN 100000
#define TT 128
#define EE 1600000
#define KK 9
#define NSPLIT 16                 // n-splits for output matmul

// Binned CSR build
#define BSH 7                     // 128 nodes per bucket
#define BMASK 127
#define NBUCK 782                 // ceil(100000/128)
#define BCAP 2560                 // avg 2046/bucket, sigma~45 -> 11 sigma headroom
#define BINB 782                  // (EE + 2047) / 2048
#define CVTB 12500                // NN*TT/4 / 256

typedef _Float16 f16;
typedef __attribute__((ext_vector_type(2))) _Float16 f16x2;
typedef __attribute__((ext_vector_type(4))) _Float16 f16x4;
typedef __attribute__((ext_vector_type(8))) _Float16 f16x8;

union HU8 { f16x8 h; int4 i; };

// ---------- layer stage (device fn): y = relu(conv_nobias(gather(xin))*inv_cnt + b) ----------
// One wave per node (grid-strided). p = lane&15 owns t = {8p..8p+7} (f16x8, 16B);
// quarter-groups q process 4 edges per 1 KiB load; packed-fp16 accumulate;
// groups combined via xor-16/32 shuffles; fp32 epilogue.
__device__ __forceinline__ void layer_stage(
    const f16x8* __restrict__ xin,
    const int* __restrict__ offsets, const int* __restrict__ col,
    const float* __restrict__ inv_cnt,
    const float* __restrict__ w9, const float* __restrict__ bptr,
    f16x8* __restrict__ yout, int nwaves)
{
    int tid = threadIdx.x;
    int lane = tid & 63;
    int q = lane >> 4;
    int p = lane & 15;
    float wr[KK];
#pragma unroll
    for (int k = 0; k < KK; k++) wr[k] = w9[k];
    float bb = bptr[0];

    for (int node = (blockIdx.x << 2) | (tid >> 6); node < NN; node += nwaves) {
        int lo = offsets[node], hi = offsets[node + 1];
        int cnt = hi - lo;
        int my_col = (lane < cnt) ? col[lo + lane] : 0;
        int jn = cnt < 64 ? cnt : 64;

        const f16 z = (f16)0;
        f16x8 acc0 = {z, z, z, z, z, z, z, z};
        f16x8 acc1 = {z, z, z, z, z, z, z, z};

        int j = 0;
        for (; j + 7 < jn; j += 8) {               // 8 edges / iter, 2 loads in flight
            int c0 = __shfl(my_col, j + q);
            int c1 = __shfl(my_col, j + 4 + q);
            f16x8 v0 = xin[(c0 << 4) | p];
            f16x8 v1 = xin[(c1 << 4) | p];
            acc0 += v0;
            acc1 += v1;
        }
        for (; j + 3 < jn; j += 4) {               // 4 edges
            int c = __shfl(my_col, j + q);
            acc0 += xin[(c << 4) | p];
        }
        if (j < jn) {                              // tail 1..3 edges
            int rem = jn - j;
            int c = __shfl(my_col, j + (q < rem ? q : 0));
            f16x8 v = xin[(c << 4) | p];
            if (q < rem) acc1 += v;
        }
        for (int k = 64; k < cnt; k++) {           // degree > 64 (effectively never)
            int c = col[lo + k];
            f16x8 v = xin[(c << 4) | p];
            if (q == 0) acc0 += v;
        }
        acc0 += acc1;

        {   // combine the 4 quarter-groups: xor-16 then xor-32
            HU8 u; u.h = acc0;
            int4 o;
            o.x = __shfl_xor(u.i.x, 16); o.y = __shfl_xor(u.i.y, 16);
            o.z = __shfl_xor(u.i.z, 16); o.w = __shfl_xor(u.i.w, 16);
            HU8 w2; w2.i = o;
            acc0 += w2.h;
            u.h = acc0;
            o.x = __shfl_xor(u.i.x, 32); o.y = __shfl_xor(u.i.y, 32);
            o.z = __shfl_xor(u.i.z, 32); o.w = __shfl_xor(u.i.w, 32);
            w2.i = o;
            acc0 += w2.h;
        }

        // fp32 epilogue: + self row, conv K=9, mean, bias, relu
        f16x8 sv = xin[(node << 4) | p];
        float A[16];
        A[4]  = (float)acc0[0] + (float)sv[0];
        A[5]  = (float)acc0[1] + (float)sv[1];
        A[6]  = (float)acc0[2] + (float)sv[2];
        A[7]  = (float)acc0[3] + (float)sv[3];
        A[8]  = (float)acc0[4] + (float)sv[4];
        A[9]  = (float)acc0[5] + (float)sv[5];
        A[10] = (float)acc0[6] + (float)sv[6];
        A[11] = (float)acc0[7] + (float)sv[7];
#pragma unroll
        for (int i = 0; i < 4; i++) {
            A[i]      = __shfl_up(A[8 + i], 1, 16);    // prev lane's a[4..7]
            A[12 + i] = __shfl_down(A[4 + i], 1, 16);  // next lane's a[0..3]
        }
        if (p == 0)  { A[0] = 0.0f; A[1] = 0.0f; A[2] = 0.0f; A[3] = 0.0f; }
        if (p == 15) { A[12] = 0.0f; A[13] = 0.0f; A[14] = 0.0f; A[15] = 0.0f; }

        float ic = inv_cnt[node];
        f16x8 o8;
#pragma unroll
        for (int i = 0; i < 8; i++) {
            float s = 0.0f;
#pragma unroll
            for (int k = 0; k < KK; k++) s += wr[k] * A[i + k];
            s = fmaxf(s * ic + bb, 0.0f);
            o8[i] = (f16)s;
        }
        if (q == 0) yout[(node << 4) | p] = o8;
    }
}

// ---------- the whole pipeline in one cooperative kernel ----------
__global__ __launch_bounds__(256, 8)
void mega_kernel(const int* __restrict__ ei, const float4* __restrict__ x,
                 const float* __restrict__ cw, const float* __restrict__ cb,
                 const float* __restrict__ Wout, const float* __restrict__ bout,
                 float* __restrict__ out,
                 f16x8* __restrict__ x16, f16x8* __restrict__ yA, f16x8* __restrict__ yB,
                 unsigned int* __restrict__ binned, int* __restrict__ gcursor,
                 int* __restrict__ part, int* __restrict__ offsets,
                 float* __restrict__ inv_cnt, int* __restrict__ col)
{
    cg::grid_group grid = cg::this_grid();
    __shared__ int binh[NBUCK];
    __shared__ int gbase[NBUCK];
    __shared__ int sm[256];
    __shared__ int bukh[128];
    __shared__ int cur[128];
    __shared__ int sc[128];
    __shared__ float red[4][3];

    int tid = threadIdx.x;
    int blk = blockIdx.x;
    int nblk = gridDim.x;
    int gid = blk * 256 + tid;

    // ===== stage A: zero gcursor + out (ws/out are poisoned before every call) =====
    for (int i = gid; i < NBUCK; i += nblk * 256) gcursor[i] = 0;
    for (int i = gid; i < TT * 3; i += nblk * 256) out[i] = 0.0f;
    grid.sync();

    // ===== stage B: bin edges by dst range + x fp32->fp16 (independent, fused) =====
    // Packed edge: (dlocal << 20) | src   (src < 2^17, dlocal < 2^7)
    for (int vb = blk; vb < BINB + CVTB; vb += nblk) {
        if (vb < BINB) {
            for (int i = tid; i < NBUCK; i += 256) binh[i] = 0;
            __syncthreads();
            int base = vb * 2048;
            unsigned int val[8];
            int bkt[8];
            int rank[8];
#pragma unroll
            for (int k = 0; k < 8; k++) {
                int e = base + k * 256 + tid;
                bkt[k] = -1;
                if (e < EE) {
                    int s = ei[e];            // src
                    int d = ei[EE + e];       // dst
                    bkt[k] = d >> BSH;
                    val[k] = ((unsigned int)(d & BMASK) << 20) | (unsigned int)s;
                    rank[k] = atomicAdd(&binh[bkt[k]], 1);
                }
            }
            __syncthreads();
            for (int i = tid; i < NBUCK; i += 256)
                gbase[i] = binh[i] ? atomicAdd(&gcursor[i], binh[i]) : 0;
            __syncthreads();
#pragma unroll
            for (int k = 0; k < 8; k++) {
                if (bkt[k] >= 0)
                    binned[(size_t)bkt[k] * BCAP + gbase[bkt[k]] + rank[k]] = val[k];
            }
            __syncthreads();
        } else {
            int i = (vb - BINB) * 256 + tid;   // over exactly NN*TT/4 float4s
            float4 v = x[i];
            f16x4 o;
            o.x = (f16)v.x; o.y = (f16)v.y; o.z = (f16)v.z; o.w = (f16)v.w;
            ((f16x4*)x16)[i] = o;
        }
    }
    grid.sync();

    // ===== stage C1: scan bucket counts -> bucket bases (block 0) =====
    if (blk == 0) {
        int base = tid * 4;
        int v[4];
        int s = 0;
#pragma unroll
        for (int k = 0; k < 4; k++) {
            int i = base + k;
            v[k] = (i < NBUCK) ? gcursor[i] : 0;
            s += v[k];
        }
        sm[tid] = s;
        __syncthreads();
        for (int off = 1; off < 256; off <<= 1) {
            int t = (tid >= off) ? sm[tid - off] : 0;
            __syncthreads();
            sm[tid] += t;
            __syncthreads();
        }
        int run = (tid == 0) ? 0 : sm[tid - 1];
#pragma unroll
        for (int k = 0; k < 4; k++) {
            int i = base + k;
            if (i < NBUCK) part[i] = run;
            run += v[k];
        }
        if (tid == 0) offsets[NN] = EE;
    }
    grid.sync();

    // ===== stage C2: per-bucket (128 nodes) hist + scan + offsets/inv_cnt + place =====
    for (int b = blk; b < NBUCK; b += nblk) {
        int cnt = gcursor[b];
        const unsigned int* ePtr = binned + (size_t)b * BCAP;
        if (tid < 128) bukh[tid] = 0;
        __syncthreads();
        for (int j = tid; j < cnt; j += 256)
            atomicAdd(&bukh[ePtr[j] >> 20], 1);
        __syncthreads();
        int d = (tid < 128) ? bukh[tid] : 0;
        if (tid < 128) sc[tid] = d;
        __syncthreads();
        for (int off = 1; off < 128; off <<= 1) {
            int t = (tid < 128 && tid >= off) ? sc[tid - off] : 0;
            __syncthreads();
            if (tid < 128) sc[tid] += t;
            __syncthreads();
        }
        if (tid < 128) {
            int node = (b << BSH) + tid;
            int pos = part[b] + sc[tid] - d;   // exclusive prefix
            if (node < NN) {
                offsets[node] = pos;
                inv_cnt[node] = 1.0f / (1.0f + (float)d);
                cur[tid] = pos;
            }
        }
        __syncthreads();
        // place: writes land in this bucket's contiguous col window (~8 KB, L2-resident)
        for (int j = tid; j < cnt; j += 256) {
            unsigned int v = ePtr[j];
            int pos = atomicAdd(&cur[v >> 20], 1);
            col[pos] = (int)(v & 0xFFFFF);
        }
        __syncthreads();
    }
    grid.sync();

    // ===== stages L1-L3: fused conv+gather layers =====
    int nwaves = nblk * 4;
    layer_stage(x16, offsets, col, inv_cnt, cw + 0 * KK, cb + 0, yA, nwaves);
    grid.sync();
    layer_stage(yA, offsets, col, inv_cnt, cw + 1 * KK, cb + 1, yB, nwaves);
    grid.sync();
    layer_stage(yB, offsets, col, inv_cnt, cw + 2 * KK, cb + 2, yA, nwaves);
    grid.sync();

    // ===== stage O: out[t,c] = b[c] + sum_n y3flat[t*NN+n] * Wout[c*NN+n] =====
    const f16* y3 = (const f16*)yA;
    for (int vb = blk; vb < TT * NSPLIT; vb += nblk) {
        int t = vb >> 4;
        int sp = vb & 15;
        const int per = NN / NSPLIT;   // 6250
        int lo = sp * per;
        int hi = lo + per;
        float a0 = 0.0f, a1 = 0.0f, a2 = 0.0f;
        for (int n = lo + tid * 2; n < hi; n += 512) {
            f16x2 v2 = *(const f16x2*)(y3 + (size_t)t * NN + n);
            float vx = (float)v2.x, vy = (float)v2.y;
            float2 wA = *(const float2*)(Wout + n);
            float2 wB = *(const float2*)(Wout + NN + n);
            float2 wC = *(const float2*)(Wout + 2 * NN + n);
            a0 += vx * wA.x + vy * wA.y;
            a1 += vx * wB.x + vy * wB.y;
            a2 += vx * wC.x + vy * wC.y;
        }
        for (int o = 32; o > 0; o >>= 1) {
            a0 += __shfl_down(a0, o);
            a1 += __shfl_down(a1, o);
            a2 += __shfl_down(a2, o);
        }
        int wave = tid >> 6;
        if ((tid & 63) == 0) {
            red[wave][0] = a0;
            red[wave][1] = a1;
            red[wave][2] = a2;
        }
        __syncthreads();
        if (tid == 0) {
            float r0 = red[0][0] + red[1][0] + red[2][0] + red[3][0];
            float r1 = red[0][1] + red[1][1] + red[2][1] + red[3][1];
            float r2 = red[0][2] + red[1][2] + red[2][2] + red[3][2];
            if (sp == 0) {
                r0 += bout[0];
                r1 += bout[1];
                r2 += bout[2];
            }
            atomicAdd(&out[t * 3 + 0], r0);
            atomicAdd(&out[t * 3 + 1], r1);
            atomicAdd(&out[t * 3 + 2], r2);
        }
        __syncthreads();   // protect red[] before next vb iteration
    }
}

extern "C" void kernel_launch(void* const* d_in, const int* in_sizes, int n_in,
                              void* d_out, int out_size, void* d_ws, size_t ws_size,
                              hipStream_t stream) {
    const int*    ei   = (const int*)d_in[1];     // [2,E]
    const float4* x    = (const float4*)d_in[0];  // [N,T]
    const float*  cw   = (const float*)d_in[2];   // [L,1,1,K]
    const float*  cb   = (const float*)d_in[3];   // [L,1]
    const float*  Wout = (const float*)d_in[4];   // [3,N]
    const float*  bout = (const float*)d_in[5];   // [3]
    float* out = (float*)d_out;                   // [T,3]

    char* ws = (char*)d_ws;
    size_t off = 0;
    auto alloc = [&](size_t bytes) -> void* {
        void* p = ws + off;
        off += (bytes + 255) & ~(size_t)255;
        return p;
    };
    f16x8*        x16     = (f16x8*)alloc((size_t)NN * TT * 2);
    f16x8*        yA      = (f16x8*)alloc((size_t)NN * TT * 2);
    f16x8*        yB      = (f16x8*)alloc((size_t)NN * TT * 2);
    unsigned int* binned  = (unsigned int*)alloc((size_t)NBUCK * BCAP * 4);
    int*          gcursor = (int*)alloc((size_t)NBUCK * 4);
    int*          part    = (int*)alloc((size_t)NBUCK * 4);
    int*          offsets = (int*)alloc((size_t)(NN + 1) * 4);
    float*        inv_cnt = (float*)alloc((size_t)NN * 4);
    int*          col     = (int*)alloc((size_t)EE * 4);

    // co-resident grid: __launch_bounds__(256,8) -> 8 blocks/CU x 256 CUs = 2048
    int nb = 0;
    int cgrid = 2048;
    if (hipOccupancyMaxActiveBlocksPerMultiprocessor(&nb, mega_kernel, 256, 0) == hipSuccess
        && nb > 0) {
        int m = nb * 256;
        if (m < cgrid) cgrid = m;
    }

    void* args[] = {
        (void*)&ei, (void*)&x, (void*)&cw, (void*)&cb, (void*)&Wout, (void*)&bout,
        (void*)&out, (void*)&x16, (void*)&yA, (void*)&yB,
        (void*)&binned, (void*)&gcursor, (void*)&part, (void*)&offsets,
        (void*)&inv_cnt, (void*)&col
    };
    hipLaunchCooperativeKernel((void*)mega_kernel, dim3(cgrid), dim3(256),
                               args, 0, stream);
}

// Round 9
// 406.705 us; speedup vs baseline: 2.9942x; 2.9942x over previous
//
#include <hip/hip_runtime.h>

// Problem constants (match reference)
#define NN 100000
#define TT 128
#define EE 1600000
#define KK 9

// Binned CSR build: 512-node buckets
#define BSH 9
#define BMASK 511
#define NBUCK 196                 // ceil(100000/512)
#define BCAP 10240                // avg 8163/bucket, sigma~90 -> 23 sigma headroom
#define EPB 4096                  // edges per bin block
#define BINB 391                  // ceil(EE/EPB)
#define CVTB 12500                // NN*TT/4 / 256

// L3+out fused kernel grid
#define L3B 2048

typedef _Float16 f16;
typedef __attribute__((ext_vector_type(4))) _Float16 f16x4;
typedef __attribute__((ext_vector_type(8))) _Float16 f16x8;

union HU8 { f16x8 h; int4 i; };

// ---------- fused: bin edges (blocks 0..BINB) + x fp32->fp16 + zero out ----------
// Packed edge: (dlocal << 20) | src   (src < 2^17, dlocal < 2^9)
__global__ void bin_cvt_kernel(const int* __restrict__ ei, int* __restrict__ gcursor,
                               unsigned int* __restrict__ binned,
                               const float4* __restrict__ x, f16x4* __restrict__ x16,
                               float* __restrict__ out) {
    __shared__ int hist[NBUCK];
    __shared__ int gbase[NBUCK];
    int tid = threadIdx.x;

    if (blockIdx.x >= BINB + CVTB) {          // one block: zero the output accumulator
        if (tid < TT * 3) out[tid] = 0.0f;
        return;
    }
    if (blockIdx.x >= BINB) {
        // cvt part: one float4 per thread over N*T/4 (exactly CVTB*256 elements)
        int i = (blockIdx.x - BINB) * 256 + tid;
        float4 v = x[i];
        f16x4 o;
        o.x = (f16)v.x; o.y = (f16)v.y; o.z = (f16)v.z; o.w = (f16)v.w;
        x16[i] = o;
        return;
    }

    if (tid < NBUCK) hist[tid] = 0;
    __syncthreads();
    int base = blockIdx.x * EPB;
    unsigned int val[16];
    short bkt[16];
    short rank[16];
#pragma unroll
    for (int k = 0; k < 16; k++) {
        int e = base + k * 256 + tid;
        bkt[k] = -1;
        if (e < EE) {
            int s = ei[e];            // src
            int d = ei[EE + e];       // dst
            bkt[k] = (short)(d >> BSH);
            val[k] = ((unsigned int)(d & BMASK) << 20) | (unsigned int)s;
            rank[k] = (short)atomicAdd(&hist[bkt[k]], 1);
        }
    }
    __syncthreads();
    if (tid < NBUCK) gbase[tid] = hist[tid] ? atomicAdd(&gcursor[tid], hist[tid]) : 0;
    __syncthreads();
#pragma unroll
    for (int k = 0; k < 16; k++) {
        if (bkt[k] >= 0)
            binned[(size_t)bkt[k] * BCAP + gbase[bkt[k]] + (int)rank[k]] = val[k];
    }
}

// ---------- per-bucket (512 nodes): bucket-base scan + hist + scan + offsets/inv_cnt + place ----------
__global__ void bucket_csr_kernel(const unsigned int* __restrict__ binned,
                                  const int* __restrict__ gcursor,
                                  int* __restrict__ offsets,
                                  float* __restrict__ inv_cnt,
                                  int* __restrict__ col) {
    __shared__ int hist[512];
    __shared__ int cur[512];
    __shared__ int sm[256];
    int b = blockIdx.x;
    int tid = threadIdx.x;

    // bucket-base scan over all 196 bucket counts (each block redoes it; ~µs)
    sm[tid] = (tid < NBUCK) ? gcursor[tid] : 0;
    __syncthreads();
    for (int off = 1; off < 256; off <<= 1) {
        int v = (tid >= off) ? sm[tid - off] : 0;
        __syncthreads();
        sm[tid] += v;
        __syncthreads();
    }
    int bucket_base = (b == 0) ? 0 : sm[b - 1];
    if (b == 0 && tid == 0) offsets[NN] = EE;
    __syncthreads();

    int cnt = gcursor[b];
    const unsigned int* ePtr = binned + (size_t)b * BCAP;
    hist[tid] = 0;
    hist[tid + 256] = 0;
    __syncthreads();
    for (int j = tid; j < cnt; j += 256)
        atomicAdd(&hist[ePtr[j] >> 20], 1);
    __syncthreads();
    // exclusive scan of 512 degree counts (thread t owns entries 2t, 2t+1)
    int d0 = hist[2 * tid], d1 = hist[2 * tid + 1];
    sm[tid] = d0 + d1;
    __syncthreads();
    for (int off = 1; off < 256; off <<= 1) {
        int v = (tid >= off) ? sm[tid - off] : 0;
        __syncthreads();
        sm[tid] += v;
        __syncthreads();
    }
    int basep = bucket_base + ((tid == 0) ? 0 : sm[tid - 1]);
    int node0 = (b << BSH) + 2 * tid;
    int p0 = basep;
    int p1 = basep + d0;
    if (node0 < NN) {
        offsets[node0] = p0;
        inv_cnt[node0] = 1.0f / (1.0f + (float)d0);
        cur[2 * tid] = p0;
    }
    if (node0 + 1 < NN) {
        offsets[node0 + 1] = p1;
        inv_cnt[node0 + 1] = 1.0f / (1.0f + (float)d1);
        cur[2 * tid + 1] = p1;
    }
    __syncthreads();
    // place: all writes land in this bucket's contiguous col window (~32 KB, L2-resident)
    for (int j = tid; j < cnt; j += 256) {
        unsigned int v = ePtr[j];
        int pos = atomicAdd(&cur[v >> 20], 1);
        col[pos] = (int)(v & 0xFFFFF);
    }
}

// ---------- shared gather+conv body (one wave per node) ----------
// p = lane&15 owns t = {8p..8p+7} (f16x8, 16B); quarter-groups q process 4 edges
// per 1 KiB load; packed-fp16 accumulate; xor-16/32 combine; fp32 conv epilogue.
// Result: s[0..7] = relu(conv(...)*ic + b) for t = 8p..8p+7, valid on ALL lanes.
__device__ __forceinline__ void gather_conv_node(
    const f16x8* __restrict__ xin, const int* __restrict__ offsets,
    const int* __restrict__ col, const float* __restrict__ inv_cnt,
    const float* wr, float bb, int node, int lane, int q, int p, float* s)
{
    int lo = offsets[node], hi = offsets[node + 1];
    int cnt = hi - lo;
    int my_col = (lane < cnt) ? col[lo + lane] : 0;
    int jn = cnt < 64 ? cnt : 64;

    const f16 z = (f16)0;
    f16x8 acc0 = {z, z, z, z, z, z, z, z};
    f16x8 acc1 = {z, z, z, z, z, z, z, z};

    int j = 0;
    for (; j + 7 < jn; j += 8) {               // 8 edges / iter, 2 loads in flight
        int c0 = __shfl(my_col, j + q);
        int c1 = __shfl(my_col, j + 4 + q);
        f16x8 v0 = xin[(c0 << 4) | p];
        f16x8 v1 = xin[(c1 << 4) | p];
        acc0 += v0;
        acc1 += v1;
    }
    for (; j + 3 < jn; j += 4) {               // 4 edges
        int c = __shfl(my_col, j + q);
        acc0 += xin[(c << 4) | p];
    }
    if (j < jn) {                              // tail 1..3 edges
        int rem = jn - j;
        int c = __shfl(my_col, j + (q < rem ? q : 0));
        f16x8 v = xin[(c << 4) | p];
        if (q < rem) acc1 += v;
    }
    for (int k = 64; k < cnt; k++) {           // degree > 64 (effectively never)
        int c = col[lo + k];
        f16x8 v = xin[(c << 4) | p];
        if (q == 0) acc0 += v;
    }
    acc0 += acc1;

    {   // combine the 4 quarter-groups: xor-16 then xor-32
        HU8 u; u.h = acc0;
        int4 o;
        o.x = __shfl_xor(u.i.x, 16); o.y = __shfl_xor(u.i.y, 16);
        o.z = __shfl_xor(u.i.z, 16); o.w = __shfl_xor(u.i.w, 16);
        HU8 w2; w2.i = o;
        acc0 += w2.h;
        u.h = acc0;
        o.x = __shfl_xor(u.i.x, 32); o.y = __shfl_xor(u.i.y, 32);
        o.z = __shfl_xor(u.i.z, 32); o.w = __shfl_xor(u.i.w, 32);
        w2.i = o;
        acc0 += w2.h;
    }

    // fp32 epilogue: + self row, conv K=9, mean, bias, relu
    f16x8 sv = xin[(node << 4) | p];
    float A[16];
    A[4]  = (float)acc0[0] + (float)sv[0];
    A[5]  = (float)acc0[1] + (float)sv[1];
    A[6]  = (float)acc0[2] + (float)sv[2];
    A[7]  = (float)acc0[3] + (float)sv[3];
    A[8]  = (float)acc0[4] + (float)sv[4];
    A[9]  = (float)acc0[5] + (float)sv[5];
    A[10] = (float)acc0[6] + (float)sv[6];
    A[11] = (float)acc0[7] + (float)sv[7];
#pragma unroll
    for (int i = 0; i < 4; i++) {
        A[i]      = __shfl_up(A[8 + i], 1, 16);    // prev lane's a[4..7]
        A[12 + i] = __shfl_down(A[4 + i], 1, 16);  // next lane's a[0..3]
    }
    if (p == 0)  { A[0] = 0.0f; A[1] = 0.0f; A[2] = 0.0f; A[3] = 0.0f; }
    if (p == 15) { A[12] = 0.0f; A[13] = 0.0f; A[14] = 0.0f; A[15] = 0.0f; }

    float ic = inv_cnt[node];
#pragma unroll
    for (int i = 0; i < 8; i++) {
        float t = 0.0f;
#pragma unroll
        for (int k = 0; k < KK; k++) t += wr[k] * A[i + k];
        s[i] = fmaxf(t * ic + bb, 0.0f);
    }
}

// ---------- layers 1-2: store y as f16x8 ----------
__global__ void fused_layer_kernel(const f16x8* __restrict__ xin,
                                   const int* __restrict__ offsets,
                                   const int* __restrict__ col,
                                   const float* __restrict__ inv_cnt,
                                   const float* __restrict__ w9,
                                   const float* __restrict__ bptr,
                                   f16x8* __restrict__ yout) {
    int tid = threadIdx.x;
    int lane = tid & 63;
    int q = lane >> 4;
    int p = lane & 15;
    int node = blockIdx.x * 4 + (tid >> 6);
    float wr[KK];
#pragma unroll
    for (int k = 0; k < KK; k++) wr[k] = w9[k];
    float s[8];
    gather_conv_node(xin, offsets, col, inv_cnt, wr, bptr[0], node, lane, q, p, s);
    if (q == 0) {
        f16x8 o;
#pragma unroll
        for (int i = 0; i < 8; i++) o[i] = (f16)s[i];
        yout[(node << 4) | p] = o;
    }
}

// ---------- layer 3 fused with output head ----------
// Reference does out = y3.reshape(-1,N) @ Wout.T: FLAT reinterpretation, not transpose.
// Node n's value at tt sits at flat f = n*128+tt -> out row t = f/NN, col nw = f-t*NN.
// Per node (non-boundary): all 128 elements share one t and a contiguous Wout run;
// per-lane partial dot -> wave reduce -> 3 LDS atomics. Boundary nodes (~127): per-elem.
__global__ void layer3_out_kernel(const f16x8* __restrict__ xin,
                                  const int* __restrict__ offsets,
                                  const int* __restrict__ col,
                                  const float* __restrict__ inv_cnt,
                                  const float* __restrict__ w9,
                                  const float* __restrict__ bptr,
                                  const float* __restrict__ Wout,
                                  const float* __restrict__ bout,
                                  float* __restrict__ out) {
    __shared__ float accL[TT * 3];
    int tid = threadIdx.x;
    for (int i = tid; i < TT * 3; i += 256) accL[i] = 0.0f;
    __syncthreads();

    int lane = tid & 63;
    int q = lane >> 4;
    int p = lane & 15;
    float wr[KK];
#pragma unroll
    for (int k = 0; k < KK; k++) wr[k] = w9[k];
    float bb = bptr[0];
    const int nwaves = L3B * 4;

    float s[8];
    for (int node = blockIdx.x * 4 + (tid >> 6); node < NN; node += nwaves) {
        gather_conv_node(xin, offsets, col, inv_cnt, wr, bb, node, lane, q, p, s);
        int f0 = node * TT;        // flat base index of this node's row
        int t0 = f0 / NN;          // output row
        int r0 = f0 - t0 * NN;     // Wout column base
        if (r0 + TT <= NN) {
            // fast path: whole row maps to out[t0][*]; quarter q owns i = {2q, 2q+1}
            float a0 = 0.0f, a1 = 0.0f, a2 = 0.0f;
            int nb = r0 + 8 * p;
#pragma unroll
            for (int ii = 0; ii < 2; ii++) {
                int i = 2 * q + ii;
                float v = s[i];
                a0 += v * Wout[nb + i];
                a1 += v * Wout[NN + nb + i];
                a2 += v * Wout[2 * NN + nb + i];
            }
            for (int o = 32; o > 0; o >>= 1) {
                a0 += __shfl_down(a0, o);
                a1 += __shfl_down(a1, o);
                a2 += __shfl_down(a2, o);
            }
            if (lane == 0) {
                atomicAdd(&accL[t0 * 3 + 0], a0);
                atomicAdd(&accL[t0 * 3 + 1], a1);
                atomicAdd(&accL[t0 * 3 + 2], a2);
            }
        } else {
            // boundary node: elements straddle two out rows; per-element accumulate
#pragma unroll
            for (int ii = 0; ii < 2; ii++) {
                int i = 2 * q + ii;
                int f = f0 + 8 * p + i;
                int t = f / NN;
                int nw = f - t * NN;
                float v = s[i];
                atomicAdd(&accL[t * 3 + 0], v * Wout[nw]);
                atomicAdd(&accL[t * 3 + 1], v * Wout[NN + nw]);
                atomicAdd(&accL[t * 3 + 2], v * Wout[2 * NN + nw]);
            }
        }
    }
    __syncthreads();
    for (int i = tid; i < TT * 3; i += 256) {
        float v = accL[i];
        if (blockIdx.x == 0) v += bout[i - (i / 3) * 3];
        atomicAdd(&out[i], v);
    }
}

extern "C" void kernel_launch(void* const* d_in, const int* in_sizes, int n_in,
                              void* d_out, int out_size, void* d_ws, size_t ws_size,
                              hipStream_t stream) {
    const float4* x    = (const float4*)d_in[0];  // [N,T]
    const int*    ei   = (const int*)d_in[1];     // [2,E]
    const float*  cw   = (const float*)d_in[2];   // [L,1,1,K]
    const float*  cb   = (const float*)d_in[3];   // [L,1]
    const float*  Wout = (const float*)d_in[4];   // [3,N]
    const float*  bout = (const float*)d_in[5];   // [3]
    float* out = (float*)d_out;                   // [T,3]

    char* ws = (char*)d_ws;
    size_t off = 0;
    auto alloc = [&](size_t bytes) -> void* {
        void* p = ws + off;
        off += (bytes + 255) & ~(size_t)255;
        return p;
    };
    f16x8*        x16     = (f16x8*)alloc((size_t)NN * TT * 2);
    f16x8*        yA      = (f16x8*)alloc((size_t)NN * TT * 2);
    f16x8*        yB      = (f16x8*)alloc((size_t)NN * TT * 2);
    unsigned int* binned  = (unsigned int*)alloc((size_t)NBUCK * BCAP * 4);
    int*          gcursor = (int*)alloc((size_t)NBUCK * 4);
    int*          offsets = (int*)alloc((size_t)(NN + 1) * 4);
    float*        inv_cnt = (float*)alloc((size_t)NN * 4);
    int*          col     = (int*)alloc((size_t)EE * 4);

    // CSR build + cvt + out-zero (ws/out are re-poisoned before every call)
    hipMemsetAsync(gcursor, 0, (size_t)NBUCK * 4, stream);
    bin_cvt_kernel<<<BINB + CVTB + 1, 256, 0, stream>>>(ei, gcursor, binned,
                                                        x, (f16x4*)x16, out);
    bucket_csr_kernel<<<NBUCK, 256, 0, stream>>>(binned, gcursor, offsets, inv_cnt, col);

    // layers 1-2 (conv commuted past gather; bias/mean folded exactly)
    fused_layer_kernel<<<NN / 4, 256, 0, stream>>>(x16, offsets, col, inv_cnt,
                                                   cw + 0 * KK, cb + 0, yA);
    fused_layer_kernel<<<NN / 4, 256, 0, stream>>>(yA, offsets, col, inv_cnt,
                                                   cw + 1 * KK, cb + 1, yB);
    // layer 3 + output head fused (y3 stays in registers)
    layer3_out_kernel<<<L3B, 256, 0, stream>>>(yB, offsets, col, inv_cnt,
                                               cw + 2 * KK, cb + 2, Wout, bout, out);
}

// Round 10
// 333.470 us; speedup vs baseline: 3.6517x; 1.2196x over previous
//
#include <hip/hip_runtime.h>

// Problem constants (match reference)
#define NN 100000
#define TT 128
#define EE 1600000
#define KK 9
#define NSPLIT 16                 // n-splits for output matmul

// Binned CSR build: 512-node buckets
#define BSH 9
#define BMASK 511
#define NBUCK 196                 // ceil(100000/512)
#define BCAP 10240                // avg 8163/bucket, sigma~90 -> 23 sigma headroom
#define EPB 4096                  // edges per bin block
#define BINB 391                  // ceil(EE/EPB)
#define CVTB 3125                 // NN*TT/4 / 1024

typedef _Float16 f16;
typedef __attribute__((ext_vector_type(2))) _Float16 f16x2;
typedef __attribute__((ext_vector_type(4))) _Float16 f16x4;
typedef __attribute__((ext_vector_type(8))) _Float16 f16x8;

union HU8 { f16x8 h; int4 i; };

// ---------- fused: bin edges (blocks 0..BINB) + x fp32->fp16 + zero out ----------
// Packed edge: (dlocal << 20) | src   (src < 2^17, dlocal < 2^9)
__global__ __launch_bounds__(1024)
void bin_cvt_kernel(const int* __restrict__ ei, int* __restrict__ gcursor,
                    unsigned int* __restrict__ binned,
                    const float4* __restrict__ x, f16x4* __restrict__ x16,
                    float* __restrict__ out) {
    __shared__ int hist[NBUCK];
    __shared__ int gbase[NBUCK];
    int tid = threadIdx.x;

    if (blockIdx.x >= BINB + CVTB) {          // one block: zero the output accumulator
        if (tid < TT * 3) out[tid] = 0.0f;
        return;
    }
    if (blockIdx.x >= BINB) {
        // cvt part: one float4 per thread over N*T/4 (exactly CVTB*1024 elements)
        int i = (blockIdx.x - BINB) * 1024 + tid;
        float4 v = x[i];
        f16x4 o;
        o.x = (f16)v.x; o.y = (f16)v.y; o.z = (f16)v.z; o.w = (f16)v.w;
        x16[i] = o;
        return;
    }

    if (tid < NBUCK) hist[tid] = 0;
    __syncthreads();
    int base = blockIdx.x * EPB;
    unsigned int val[4];
    short bkt[4];
    short rank[4];
#pragma unroll
    for (int k = 0; k < 4; k++) {
        int e = base + k * 1024 + tid;
        bkt[k] = -1;
        if (e < EE) {
            int s = ei[e];            // src
            int d = ei[EE + e];       // dst
            bkt[k] = (short)(d >> BSH);
            val[k] = ((unsigned int)(d & BMASK) << 20) | (unsigned int)s;
            rank[k] = (short)atomicAdd(&hist[bkt[k]], 1);
        }
    }
    __syncthreads();
    if (tid < NBUCK) gbase[tid] = hist[tid] ? atomicAdd(&gcursor[tid], hist[tid]) : 0;
    __syncthreads();
#pragma unroll
    for (int k = 0; k < 4; k++) {
        if (bkt[k] >= 0)
            binned[(size_t)bkt[k] * BCAP + gbase[bkt[k]] + (int)rank[k]] = val[k];
    }
}

// ---------- per-bucket (512 nodes): bucket-base scan + hist + scan + offsets/inv_cnt + place ----------
__global__ __launch_bounds__(1024)
void bucket_csr_kernel(const unsigned int* __restrict__ binned,
                       const int* __restrict__ gcursor,
                       int* __restrict__ offsets,
                       float* __restrict__ inv_cnt,
                       int* __restrict__ col) {
    __shared__ int hist[512];
    __shared__ int cur[512];
    __shared__ int smB[256];
    __shared__ int sc[512];
    int b = blockIdx.x;
    int tid = threadIdx.x;

    // bucket-base scan over all 196 bucket counts (threads 0..255; ~µs)
    if (tid < 256) smB[tid] = (tid < NBUCK) ? gcursor[tid] : 0;
    __syncthreads();
    for (int off = 1; off < 256; off <<= 1) {
        int v = 0;
        if (tid < 256 && tid >= off) v = smB[tid - off];
        __syncthreads();
        if (tid < 256) smB[tid] += v;
        __syncthreads();
    }
    int bucket_base = (b == 0) ? 0 : smB[b - 1];
    if (b == 0 && tid == 0) offsets[NN] = EE;

    int cnt = gcursor[b];
    const unsigned int* ePtr = binned + (size_t)b * BCAP;
    if (tid < 512) hist[tid] = 0;
    __syncthreads();
    for (int j = tid; j < cnt; j += 1024)          // ~8 iterations
        atomicAdd(&hist[ePtr[j] >> 20], 1);
    __syncthreads();
    int d = (tid < 512) ? hist[tid] : 0;
    if (tid < 512) sc[tid] = d;
    __syncthreads();
    for (int off = 1; off < 512; off <<= 1) {      // inclusive scan of 512 degrees
        int v = 0;
        if (tid < 512 && tid >= off) v = sc[tid - off];
        __syncthreads();
        if (tid < 512) sc[tid] += v;
        __syncthreads();
    }
    if (tid < 512) {
        int node = (b << BSH) + tid;
        int pos = bucket_base + sc[tid] - d;       // exclusive prefix
        if (node < NN) {
            offsets[node] = pos;
            inv_cnt[node] = 1.0f / (1.0f + (float)d);
            cur[tid] = pos;
        }
    }
    __syncthreads();
    // place: all writes land in this bucket's contiguous col window (~32 KB, L2-resident)
    for (int j = tid; j < cnt; j += 1024) {        // ~8 iterations
        unsigned int v = ePtr[j];
        int pos = atomicAdd(&cur[v >> 20], 1);
        col[pos] = (int)(v & 0xFFFFF);
    }
}

// ---------- shared gather+conv body (one wave per node) ----------
// p = lane&15 owns t = {8p..8p+7} (f16x8, 16B); quarter-groups q process 4 edges
// per 1 KiB load; packed-fp16 accumulate; xor-16/32 combine; fp32 conv epilogue.
__device__ __forceinline__ void gather_conv_node(
    const f16x8* __restrict__ xin, const int* __restrict__ offsets,
    const int* __restrict__ col, const float* __restrict__ inv_cnt,
    const float* wr, float bb, int node, int lane, int q, int p, float* s)
{
    int lo = offsets[node], hi = offsets[node + 1];
    int cnt = hi - lo;
    int my_col = (lane < cnt) ? col[lo + lane] : 0;
    int jn = cnt < 64 ? cnt : 64;

    const f16 z = (f16)0;
    f16x8 acc0 = {z, z, z, z, z, z, z, z};
    f16x8 acc1 = {z, z, z, z, z, z, z, z};

    int j = 0;
    for (; j + 7 < jn; j += 8) {               // 8 edges / iter, 2 loads in flight
        int c0 = __shfl(my_col, j + q);
        int c1 = __shfl(my_col, j + 4 + q);
        f16x8 v0 = xin[(c0 << 4) | p];
        f16x8 v1 = xin[(c1 << 4) | p];
        acc0 += v0;
        acc1 += v1;
    }
    for (; j + 3 < jn; j += 4) {               // 4 edges
        int c = __shfl(my_col, j + q);
        acc0 += xin[(c << 4) | p];
    }
    if (j < jn) {                              // tail 1..3 edges
        int rem = jn - j;
        int c = __shfl(my_col, j + (q < rem ? q : 0));
        f16x8 v = xin[(c << 4) | p];
        if (q < rem) acc1 += v;
    }
    for (int k = 64; k < cnt; k++) {           // degree > 64 (effectively never)
        int c = col[lo + k];
        f16x8 v = xin[(c << 4) | p];
        if (q == 0) acc0 += v;
    }
    acc0 += acc1;

    {   // combine the 4 quarter-groups: xor-16 then xor-32
        HU8 u; u.h = acc0;
        int4 o;
        o.x = __shfl_xor(u.i.x, 16); o.y = __shfl_xor(u.i.y, 16);
        o.z = __shfl_xor(u.i.z, 16); o.w = __shfl_xor(u.i.w, 16);
        HU8 w2; w2.i = o;
        acc0 += w2.h;
        u.h = acc0;
        o.x = __shfl_xor(u.i.x, 32); o.y = __shfl_xor(u.i.y, 32);
        o.z = __shfl_xor(u.i.z, 32); o.w = __shfl_xor(u.i.w, 32);
        w2.i = o;
        acc0 += w2.h;
    }

    // fp32 epilogue: + self row, conv K=9, mean, bias, relu
    f16x8 sv = xin[(node << 4) | p];
    float A[16];
    A[4]  = (float)acc0[0] + (float)sv[0];
    A[5]  = (float)acc0[1] + (float)sv[1];
    A[6]  = (float)acc0[2] + (float)sv[2];
    A[7]  = (float)acc0[3] + (float)sv[3];
    A[8]  = (float)acc0[4] + (float)sv[4];
    A[9]  = (float)acc0[5] + (float)sv[5];
    A[10] = (float)acc0[6] + (float)sv[6];
    A[11] = (float)acc0[7] + (float)sv[7];
#pragma unroll
    for (int i = 0; i < 4; i++) {
        A[i]      = __shfl_up(A[8 + i], 1, 16);    // prev lane's a[4..7]
        A[12 + i] = __shfl_down(A[4 + i], 1, 16);  // next lane's a[0..3]
    }
    if (p == 0)  { A[0] = 0.0f; A[1] = 0.0f; A[2] = 0.0f; A[3] = 0.0f; }
    if (p == 15) { A[12] = 0.0f; A[13] = 0.0f; A[14] = 0.0f; A[15] = 0.0f; }

    float ic = inv_cnt[node];
#pragma unroll
    for (int i = 0; i < 8; i++) {
        float t = 0.0f;
#pragma unroll
        for (int k = 0; k < KK; k++) t += wr[k] * A[i + k];
        s[i] = fmaxf(t * ic + bb, 0.0f);
    }
}

// ---------- layers: store y as f16x8 (one wave per node, one-shot blocks) ----------
__global__ void fused_layer_kernel(const f16x8* __restrict__ xin,
                                   const int* __restrict__ offsets,
                                   const int* __restrict__ col,
                                   const float* __restrict__ inv_cnt,
                                   const float* __restrict__ w9,
                                   const float* __restrict__ bptr,
                                   f16x8* __restrict__ yout) {
    int tid = threadIdx.x;
    int lane = tid & 63;
    int q = lane >> 4;
    int p = lane & 15;
    int node = blockIdx.x * 4 + (tid >> 6);
    float wr[KK];
#pragma unroll
    for (int k = 0; k < KK; k++) wr[k] = w9[k];
    float s[8];
    gather_conv_node(xin, offsets, col, inv_cnt, wr, bptr[0], node, lane, q, p, s);
    if (q == 0) {
        f16x8 o;
#pragma unroll
        for (int i = 0; i < 8; i++) o[i] = (f16)s[i];
        yout[(node << 4) | p] = o;
    }
}

// out[t,c] = b[c] + sum_n y3flat[t*NN + n] * Wout[c*NN + n]   (flat reinterpret view)
// (TT x NSPLIT) grid = 2048 blocks; Wout (1.2 MB) stays L2-resident; no LDS staging.
__global__ void out_kernel(const f16* __restrict__ y3, const float* __restrict__ Wout,
                           const float* __restrict__ bout, float* __restrict__ out) {
    int t = blockIdx.x;
    int sp = blockIdx.y;
    int tid = threadIdx.x;
    const int per = NN / NSPLIT;   // 6250
    int lo = sp * per;
    int hi = lo + per;
    float a0 = 0.0f, a1 = 0.0f, a2 = 0.0f;
    for (int n = lo + tid * 2; n < hi; n += 512) {
        f16x2 v2 = *(const f16x2*)(y3 + (size_t)t * NN + n);
        float vx = (float)v2.x, vy = (float)v2.y;
        float2 wA = *(const float2*)(Wout + n);
        float2 wB = *(const float2*)(Wout + NN + n);
        float2 wC = *(const float2*)(Wout + 2 * NN + n);
        a0 += vx * wA.x + vy * wA.y;
        a1 += vx * wB.x + vy * wB.y;
        a2 += vx * wC.x + vy * wC.y;
    }
    for (int o = 32; o > 0; o >>= 1) {
        a0 += __shfl_down(a0, o);
        a1 += __shfl_down(a1, o);
        a2 += __shfl_down(a2, o);
    }
    __shared__ float red[4][3];
    int wave = tid >> 6;
    if ((tid & 63) == 0) {
        red[wave][0] = a0;
        red[wave][1] = a1;
        red[wave][2] = a2;
    }
    __syncthreads();
    if (tid == 0) {
        float r0 = red[0][0] + red[1][0] + red[2][0] + red[3][0];
        float r1 = red[0][1] + red[1][1] + red[2][1] + red[3][1];
        float r2 = red[0][2] + red[1][2] + red[2][2] + red[3][2];
        if (sp == 0) {
            r0 += bout[0];
            r1 += bout[1];
            r2 += bout[2];
        }
        atomicAdd(&out[t * 3 + 0], r0);
        atomicAdd(&out[t * 3 + 1], r1);
        atomicAdd(&out[t * 3 + 2], r2);
    }
}

extern "C" void kernel_launch(void* const* d_in, const int* in_sizes, int n_in,
                              void* d_out, int out_size, void* d_ws, size_t ws_size,
                              hipStream_t stream) {
    const float4* x    = (const float4*)d_in[0];  // [N,T]
    const int*    ei   = (const int*)d_in[1];     // [2,E]
    const float*  cw   = (const float*)d_in[2];   // [L,1,1,K]
    const float*  cb   = (const float*)d_in[3];   // [L,1]
    const float*  Wout = (const float*)d_in[4];   // [3,N]
    const float*  bout = (const float*)d_in[5];   // [3]
    float* out = (float*)d_out;                   // [T,3]

    char* ws = (char*)d_ws;
    size_t off = 0;
    auto alloc = [&](size_t bytes) -> void* {
        void* p = ws + off;
        off += (bytes + 255) & ~(size_t)255;
        return p;
    };
    f16x8*        x16     = (f16x8*)alloc((size_t)NN * TT * 2);
    f16x8*        yA      = (f16x8*)alloc((size_t)NN * TT * 2);
    f16x8*        yB      = (f16x8*)alloc((size_t)NN * TT * 2);
    unsigned int* binned  = (unsigned int*)alloc((size_t)NBUCK * BCAP * 4);
    int*          gcursor = (int*)alloc((size_t)NBUCK * 4);
    int*          offsets = (int*)alloc((size_t)(NN + 1) * 4);
    float*        inv_cnt = (float*)alloc((size_t)NN * 4);
    int*          col     = (int*)alloc((size_t)EE * 4);

    // CSR build + cvt + out-zero (ws/out are re-poisoned before every call)
    hipMemsetAsync(gcursor, 0, (size_t)NBUCK * 4, stream);
    bin_cvt_kernel<<<BINB + CVTB + 1, 1024, 0, stream>>>(ei, gcursor, binned,
                                                         x, (f16x4*)x16, out);
    bucket_csr_kernel<<<NBUCK, 1024, 0, stream>>>(binned, gcursor, offsets, inv_cnt, col);

    // 3 fused layers (conv commuted past gather; bias/mean folded exactly)
    fused_layer_kernel<<<NN / 4, 256, 0, stream>>>(x16, offsets, col, inv_cnt,
                                                   cw + 0 * KK, cb + 0, yA);
    fused_layer_kernel<<<NN / 4, 256, 0, stream>>>(yA, offsets, col, inv_cnt,
                                                   cw + 1 * KK, cb + 1, yB);
    fused_layer_kernel<<<NN / 4, 256, 0, stream>>>(yB, offsets, col, inv_cnt,
                                                   cw + 2 * KK, cb + 2, yA);

    // output head (y3 = yA already has relu/mean applied; out pre-zeroed by bin_cvt)
    out_kernel<<<dim3(TT, NSPLIT), 256, 0, stream>>>((const f16*)yA, Wout, bout, out);
}